// Round 1
// baseline (121.470 us; speedup 1.0000x reference)
//
#include <hip/hip_runtime.h>

// GRU stacked: G=2 layers, H=2, T=8, B=2097152.
// ret[b,t,h] = hidden of last layer at step t; loss = mean((ret-labels)^2).
// One thread per batch element; everything in registers; weights wave-uniform.

__device__ __forceinline__ float fsigmoid(float x) {
    // 1/(1+exp(-x)) via 2^y; safe at both saturations.
    float e = __builtin_amdgcn_exp2f(-1.442695040888963f * x);
    return __builtin_amdgcn_rcpf(1.0f + e);
}

__device__ __forceinline__ float ftanh(float x) {
    // tanh(x) = 2/(1+exp(-2x)) - 1; safe at both saturations.
    float e = __builtin_amdgcn_exp2f(-2.885390081777927f * x);
    return fmaf(2.0f, __builtin_amdgcn_rcpf(1.0f + e), -1.0f);
}

__global__ __launch_bounds__(256) void gru_fused(
    const float* __restrict__ inputs,   // (B, 2)
    const float* __restrict__ labels,   // (B, 8, 2)
    const float* __restrict__ w_ih,     // (2, 6, 2)
    const float* __restrict__ w_hh,     // (2, 6, 2)
    const float* __restrict__ b_ih,     // (2, 6)
    float* __restrict__ out,            // (B, 8, 2)
    double* __restrict__ loss_acc,
    int B)
{
    const int b = blockIdx.x * blockDim.x + threadIdx.x;
    if (b >= B) return;

    // Wave-uniform weight loads -> scalar registers.
    float wih[2][6][2], whh[2][6][2], bih[2][6];
#pragma unroll
    for (int g = 0; g < 2; ++g) {
#pragma unroll
        for (int j = 0; j < 6; ++j) {
            wih[g][j][0] = w_ih[g * 12 + j * 2 + 0];
            wih[g][j][1] = w_ih[g * 12 + j * 2 + 1];
            whh[g][j][0] = w_hh[g * 12 + j * 2 + 0];
            whh[g][j][1] = w_hh[g * 12 + j * 2 + 1];
            bih[g][j]    = b_ih[g * 6 + j];
        }
    }

    const float2 x = reinterpret_cast<const float2*>(inputs)[b];
    const float4* labv = reinterpret_cast<const float4*>(labels) + (size_t)b * 4;
    float4 lab[4];
#pragma unroll
    for (int q = 0; q < 4; ++q) lab[q] = labv[q];   // issued early, hides latency

    float h[2][2] = {{0.f, 0.f}, {0.f, 0.f}};
    float o0 = x.x, o1 = x.y;
    float res[16];

#pragma unroll
    for (int t = 0; t < 8; ++t) {
#pragma unroll
        for (int g = 0; g < 2; ++g) {
            float gi[6], gh[6];
#pragma unroll
            for (int j = 0; j < 6; ++j) {
                gi[j] = fmaf(o0, wih[g][j][0], fmaf(o1, wih[g][j][1], bih[g][j]));
                gh[j] = fmaf(h[g][0], whh[g][j][0], h[g][1] * whh[g][j][1]);
            }
            const float r0 = fsigmoid(gi[0] + gh[0]);
            const float r1 = fsigmoid(gi[1] + gh[1]);
            const float z0 = fsigmoid(gi[2] + gh[2]);
            const float z1 = fsigmoid(gi[3] + gh[3]);
            const float n0 = ftanh(fmaf(r0, gh[4], gi[4]));
            const float n1 = ftanh(fmaf(r1, gh[5], gi[5]));
            // h' = (1-z)*n + z*h = n + z*(h-n)
            h[g][0] = fmaf(z0, h[g][0] - n0, n0);
            h[g][1] = fmaf(z1, h[g][1] - n1, n1);
            o0 = h[g][0];
            o1 = h[g][1];
        }
        res[t * 2 + 0] = o0;
        res[t * 2 + 1] = o1;
    }

    // Store ret (4x float4 = 64B contiguous per thread) + local squared-error sum.
    float4* outv = reinterpret_cast<float4*>(out) + (size_t)b * 4;
    float lsum = 0.f;
#pragma unroll
    for (int q = 0; q < 4; ++q) {
        const float4 ov = make_float4(res[q * 4 + 0], res[q * 4 + 1],
                                      res[q * 4 + 2], res[q * 4 + 3]);
        outv[q] = ov;
        const float d0 = ov.x - lab[q].x;
        const float d1 = ov.y - lab[q].y;
        const float d2 = ov.z - lab[q].z;
        const float d3 = ov.w - lab[q].w;
        lsum += d0 * d0 + d1 * d1 + d2 * d2 + d3 * d3;
    }

    // Wave64 shuffle reduce -> LDS across 4 waves -> one double atomic per block.
#pragma unroll
    for (int off = 32; off > 0; off >>= 1)
        lsum += __shfl_down(lsum, off, 64);
    __shared__ float wsum[4];
    const int lane = threadIdx.x & 63;
    const int wid  = threadIdx.x >> 6;
    if (lane == 0) wsum[wid] = lsum;
    __syncthreads();
    if (threadIdx.x == 0) {
        const float s = (wsum[0] + wsum[1]) + (wsum[2] + wsum[3]);
        atomicAdd(loss_acc, (double)s);
    }
}

__global__ void gru_loss_finalize(const double* __restrict__ acc,
                                  float* __restrict__ loss_out,
                                  double inv_n)
{
    *loss_out = (float)(*acc * inv_n);
}

extern "C" void kernel_launch(void* const* d_in, const int* in_sizes, int n_in,
                              void* d_out, int out_size, void* d_ws, size_t ws_size,
                              hipStream_t stream) {
    const float* inputs = (const float*)d_in[0];
    const float* labels = (const float*)d_in[1];
    const float* w_ih   = (const float*)d_in[2];
    const float* w_hh   = (const float*)d_in[3];
    const float* b_ih   = (const float*)d_in[4];
    float* out  = (float*)d_out;
    double* acc = (double*)d_ws;

    const int B  = in_sizes[0] / 2;   // inputs is (B, H=2)
    const int NE = B * 16;            // B*T*H ret elements

    hipMemsetAsync(d_ws, 0, sizeof(double), stream);

    const int block = 256;
    const int grid  = (B + block - 1) / block;
    gru_fused<<<grid, block, 0, stream>>>(inputs, labels, w_ih, w_hh, b_ih, out, acc, B);
    gru_loss_finalize<<<1, 1, 0, stream>>>(acc, out + NE, 1.0 / (double)NE);
}